// Round 5
// baseline (995.209 us; speedup 1.0000x reference)
//
#include <hip/hip_runtime.h>
#include <hip/hip_cooperative_groups.h>

namespace cg = cooperative_groups;

#define VOCAB 1000000
#define NUM_TABLES 10
#define OUT_SIZE 26
#define BUCKET_BITS 12
#define BPB 4096                 // bins per bucket
#define NBUCKETS 245             // ceil(1e6/4096)
#define CHUNK 4096               // indices per scatter block
#define MAXSRC 1024              // max source chunks (n <= 4.19M)
#define GSTRIDE 256              // gs32 row stride per src (>= NBUCKETS)
#define GBLK 1024                // cooperative grid: 4 blocks/CU x 256 CUs
#define GTHR 256
#define NGROUPS (VOCAB / 4)      // 250000 4-row groups
#define GPB 245                  // groups per block in reduce: ceil(250000/1024)
#define NSERIES 30               // 10 tables x 3 dims
#define PSTRIDE (GBLK * 4)       // partials per series: one per (block, wave) = 4096

// ==================== shared phase bodies ====================

__device__ inline float wave_reduce(float v) {
#pragma unroll
    for (int o = 32; o > 0; o >>= 1) v += __shfl_down(v, o, 64);
    return v;
}

// Phase 1: partition CHUNK indices by bucket (idx>>12) into this block's
// PRIVATE dense region of scat. LDS-staged permutation, coalesced dump.
// smem: lcount[256] | sc[256] | stage[4096 u16]  (10.25 KB of the 16 KB block)
__device__ void phase_scatter(const int* __restrict__ idx, int n, int nsrc,
                              unsigned short* __restrict__ scat,
                              unsigned int* __restrict__ gs32,
                              unsigned int* smem, int blk)
{
    unsigned int* lcount = smem;
    unsigned int* sc = smem + 256;
    unsigned short* stage = (unsigned short*)(smem + 512);
    const int tid = threadIdx.x;
    lcount[tid] = 0u;
    __syncthreads();

    const int4* idx4 = (const int4*)idx;
    const int n4 = n >> 2;
    const int base4 = blk * (CHUNK / 4);
    int4 q[4];
    bool val[4];
    unsigned rank[16], bkt[16];
#pragma unroll
    for (int j = 0; j < 4; ++j) {
        int i4 = base4 + j * 256 + tid;
        val[j] = (i4 < n4);
        if (val[j]) q[j] = idx4[i4];
    }
#pragma unroll
    for (int j = 0; j < 4; ++j) {
        if (val[j]) {
            unsigned v[4] = {(unsigned)q[j].x, (unsigned)q[j].y, (unsigned)q[j].z, (unsigned)q[j].w};
#pragma unroll
            for (int e = 0; e < 4; ++e) {
                bkt[j * 4 + e] = v[e] >> BUCKET_BITS;
                rank[j * 4 + e] = atomicAdd(&lcount[bkt[j * 4 + e]], 1u);
            }
        }
    }
    // tail (n%4): last source block, thread 0 (dead code for n=4M)
    unsigned trank[3], tbkt[3];
    int tcnt = 0;
    if (blk == nsrc - 1 && tid == 0) {
        for (int i = n4 * 4; i < n; ++i) {
            unsigned u = (unsigned)idx[i];
            tbkt[tcnt] = u >> BUCKET_BITS;
            trank[tcnt] = atomicAdd(&lcount[tbkt[tcnt]], 1u);
            ++tcnt;
        }
    }
    __syncthreads();
    // inclusive scan over 245 bucket counts (padded to 256)
    unsigned cnt = (tid < NBUCKETS) ? lcount[tid] : 0u;
    sc[tid] = cnt;
    __syncthreads();
#pragma unroll
    for (int off = 1; off < 256; off <<= 1) {
        unsigned v = sc[tid];
        unsigned a = (tid >= off) ? sc[tid - off] : 0u;
        __syncthreads();
        sc[tid] = v + a;
        __syncthreads();
    }
    unsigned excl = sc[tid] - cnt;
    if (tid < NBUCKETS) gs32[(size_t)blk * GSTRIDE + tid] = excl | (cnt << 16);
    lcount[tid] = excl;   // reuse as per-bucket base
    __syncthreads();
    // pass 2: scatter into LDS stage (unique positions, no atomics)
#pragma unroll
    for (int j = 0; j < 4; ++j) {
        if (val[j]) {
            unsigned v[4] = {(unsigned)q[j].x, (unsigned)q[j].y, (unsigned)q[j].z, (unsigned)q[j].w};
#pragma unroll
            for (int e = 0; e < 4; ++e) {
                unsigned k = j * 4 + e;
                stage[lcount[bkt[k]] + rank[k]] = (unsigned short)(v[e] & (BPB - 1));
            }
        }
    }
    if (blk == nsrc - 1 && tid == 0) {
        for (int i = 0; i < tcnt; ++i) {
            unsigned u = (unsigned)idx[n4 * 4 + i];
            stage[lcount[tbkt[i]] + trank[i]] = (unsigned short)(u & (BPB - 1));
        }
    }
    __syncthreads();
    // coalesced dump: 4096 u16 = 512 uint4
    uint4* dst = (uint4*)(scat + (size_t)blk * CHUNK);
    const uint4* src = (const uint4*)stage;
#pragma unroll
    for (int j = 0; j < 2; ++j) dst[j * 256 + tid] = src[j * 256 + tid];
}

// Phase 2: one block per bucket; wave-cooperative gather (lanes stride each
// contiguous per-src segment => coalesced), LDS hist, coalesced dump.
__device__ void phase_hist(const unsigned short* __restrict__ scat,
                           const unsigned int* __restrict__ gs32, int nsrc,
                           unsigned int* __restrict__ hist,
                           unsigned int* h, int b)
{
    const int tid = threadIdx.x;
#pragma unroll
    for (int i = 0; i < 4; ++i) ((uint4*)h)[i * 256 + tid] = make_uint4(0u, 0u, 0u, 0u);
    __syncthreads();
    const int wave = tid >> 6, lane = tid & 63;
    for (int s = wave; s < nsrc; s += 4) {
        unsigned g32 = gs32[(size_t)s * GSTRIDE + b];   // wave-uniform broadcast
        unsigned st = g32 & 0xffffu, c = g32 >> 16;
        const unsigned short* p = scat + (size_t)s * CHUNK + st;
        for (unsigned k = lane; k < c; k += 64)
            atomicAdd(&h[p[k]], 1u);
    }
    __syncthreads();
    int nb4 = min(BPB, VOCAB - b * BPB) >> 2;   // 1024 (144 for b=244)
    uint4* dst = (uint4*)(hist + (size_t)b * BPB);
    const uint4* src = (const uint4*)h;
#pragma unroll
    for (int i = 0; i < 4; ++i) {
        int o = i * 256 + tid;
        if (o < nb4) dst[o] = src[o];
    }
}

// Phase 3: block blk owns 245 consecutive 4-row groups; hist group loaded
// ONCE into registers and reused across all 10 tables (kills the 10x hist
// re-read of the split design). Per-wave partials, no __syncthreads.
__device__ void phase_reduce(const float* __restrict__ W,
                             const unsigned int* __restrict__ hist,
                             float* __restrict__ partials, int blk)
{
    const int tid = threadIdx.x;
    const int g = blk * GPB + tid;
    const bool act = (tid < GPB) && (g < NGROUPS);
    uint4 c4 = make_uint4(0u, 0u, 0u, 0u);
    if (act) c4 = ((const uint4*)hist)[g];
    const float c0 = (float)c4.x, c1 = (float)c4.y, c2 = (float)c4.z, c3 = (float)c4.w;
    const int wave = tid >> 6, lane = tid & 63;
#pragma unroll 2
    for (int t = 0; t < NUM_TABLES; ++t) {
        float a0 = 0.f, a1 = 0.f, a2 = 0.f;
        if (act) {
            const float4* __restrict__ W4 = (const float4*)(W + (size_t)t * VOCAB * 3);
            float4 w0 = W4[3 * g + 0];
            float4 w1 = W4[3 * g + 1];
            float4 w2 = W4[3 * g + 2];
            a0 = c0 * w0.x + c1 * w0.w + c2 * w1.z + c3 * w2.y;
            a1 = c0 * w0.y + c1 * w1.x + c2 * w1.w + c3 * w2.z;
            a2 = c0 * w0.z + c1 * w1.y + c2 * w2.x + c3 * w2.w;
        }
        a0 = wave_reduce(a0);
        a1 = wave_reduce(a1);
        a2 = wave_reduce(a2);
        if (lane == 0) {
            const int pb = blk * 4 + wave;
            partials[(size_t)(t * 3 + 0) * PSTRIDE + pb] = a0;
            partials[(size_t)(t * 3 + 1) * PSTRIDE + pb] = a1;
            partials[(size_t)(t * 3 + 2) * PSTRIDE + pb] = a2;
        }
    }
}

// Phase 4: 8 threads per series reduce 4096 per-wave partials, then map to out.
__device__ void phase_final(const float* __restrict__ partials,
                            float* __restrict__ out, float* smf)
{
    const int tid = threadIdx.x;
    const int srs = tid >> 3, j = tid & 7;
    float v = 0.f;
    if (srs < NSERIES) {
        const float* p = partials + (size_t)srs * PSTRIDE;
        for (int i = j; i < PSTRIDE; i += 8) v += p[i];
    }
#pragma unroll
    for (int off = 4; off > 0; off >>= 1) v += __shfl_down(v, off, 8);
    if (srs < NSERIES && j == 0) smf[srs] = v;
    __syncthreads();
    if (tid < OUT_SIZE) {
        float r;
        if (tid < 15) r = smf[tid];
        else if (tid == 15) r = smf[15] + smf[16] + smf[17];
        else if (tid == 16) r = smf[18] + smf[19] + smf[20];
        else r = smf[tid + 4];
        out[tid] = r;
    }
}

// ==================== mono cooperative kernel ====================

__global__ void __launch_bounds__(GTHR, 4) mono_kernel(
    const int* __restrict__ idx, int n, int nsrc,
    const float* __restrict__ W,
    unsigned short* __restrict__ scat,
    unsigned int* __restrict__ gs32,
    unsigned int* __restrict__ hist,
    float* __restrict__ partials,
    float* __restrict__ out)
{
    cg::grid_group grid = cg::this_grid();
    __shared__ __align__(16) unsigned int smem[BPB];   // 16 KB, reused per phase
    const int blk = blockIdx.x;

    if (blk < nsrc) phase_scatter(idx, n, nsrc, scat, gs32, smem, blk);
    __threadfence();
    grid.sync();
    if (blk < NBUCKETS) phase_hist(scat, gs32, nsrc, hist, smem, blk);
    __threadfence();
    grid.sync();
    phase_reduce(W, hist, partials, blk);
    __threadfence();
    grid.sync();
    if (blk == 0) phase_final(partials, out, (float*)smem);
}

// ==================== split-launch fallback (same phases) ====================

__global__ void __launch_bounds__(GTHR) k_scatter(const int* __restrict__ idx, int n, int nsrc,
                                                  unsigned short* __restrict__ scat,
                                                  unsigned int* __restrict__ gs32) {
    __shared__ __align__(16) unsigned int smem[BPB];
    if ((int)blockIdx.x < nsrc) phase_scatter(idx, n, nsrc, scat, gs32, smem, blockIdx.x);
}

__global__ void __launch_bounds__(GTHR) k_hist(const unsigned short* __restrict__ scat,
                                               const unsigned int* __restrict__ gs32, int nsrc,
                                               unsigned int* __restrict__ hist) {
    __shared__ __align__(16) unsigned int smem[BPB];
    phase_hist(scat, gs32, nsrc, hist, smem, blockIdx.x);
}

__global__ void __launch_bounds__(GTHR) k_reduce(const float* __restrict__ W,
                                                 const unsigned int* __restrict__ hist,
                                                 float* __restrict__ partials) {
    phase_reduce(W, hist, partials, blockIdx.x);
}

__global__ void __launch_bounds__(GTHR) k_final(const float* __restrict__ partials,
                                                float* __restrict__ out) {
    __shared__ __align__(16) float smf[32];
    phase_final(partials, out, smf);
}

// ==================== size fallback (global-atomic hist, proven) ====================

__global__ void zero_kernel_fb(unsigned int* __restrict__ hist, float* __restrict__ out) {
    int i = blockIdx.x * blockDim.x + threadIdx.x;
    int n4 = VOCAB / 4;
    if (i < n4) ((uint4*)hist)[i] = make_uint4(0u, 0u, 0u, 0u);
    if (i < OUT_SIZE) out[i] = 0.0f;
}

__global__ void hist_kernel_fb(const int* __restrict__ idx, unsigned int* __restrict__ hist, int n) {
    int i = blockIdx.x * blockDim.x + threadIdx.x;
    int i4 = i * 4;
    if (i4 + 3 < n) {
        int4 v = ((const int4*)idx)[i];
        atomicAdd(&hist[v.x], 1u);
        atomicAdd(&hist[v.y], 1u);
        atomicAdd(&hist[v.z], 1u);
        atomicAdd(&hist[v.w], 1u);
    } else {
        for (int j = i4; j < n; ++j) atomicAdd(&hist[idx[j]], 1u);
    }
}

__global__ void __launch_bounds__(256) reduce_kernel_fb(const float* __restrict__ W,
                                                        const unsigned int* __restrict__ hist,
                                                        float* __restrict__ out) {
    const int t = blockIdx.x / 64;
    const int b = blockIdx.x % 64;
    const float4* __restrict__ W4 = (const float4*)(W + (size_t)t * VOCAB * 3);
    const uint4* __restrict__ h4 = (const uint4*)hist;
    const int ngroups = VOCAB / 4;
    float a0 = 0.f, a1 = 0.f, a2 = 0.f;
    const int stride = 64 * 256;
    for (int g = b * 256 + (int)threadIdx.x; g < ngroups; g += stride) {
        uint4 c4 = h4[g];
        float4 w0 = W4[3 * g + 0];
        float4 w1 = W4[3 * g + 1];
        float4 w2 = W4[3 * g + 2];
        float c0 = (float)c4.x, c1 = (float)c4.y, c2 = (float)c4.z, c3 = (float)c4.w;
        a0 += c0 * w0.x + c1 * w0.w + c2 * w1.z + c3 * w2.y;
        a1 += c0 * w0.y + c1 * w1.x + c2 * w1.w + c3 * w2.z;
        a2 += c0 * w0.z + c1 * w1.y + c2 * w2.x + c3 * w2.w;
    }
    a0 = wave_reduce(a0);
    a1 = wave_reduce(a1);
    a2 = wave_reduce(a2);
    __shared__ float s[3][4];
    int wave = threadIdx.x >> 6;
    int lane = threadIdx.x & 63;
    if (lane == 0) { s[0][wave] = a0; s[1][wave] = a1; s[2][wave] = a2; }
    __syncthreads();
    if (threadIdx.x == 0) {
        float r0 = s[0][0] + s[0][1] + s[0][2] + s[0][3];
        float r1 = s[1][0] + s[1][1] + s[1][2] + s[1][3];
        float r2 = s[2][0] + s[2][1] + s[2][2] + s[2][3];
        if (t == 5) atomicAdd(&out[15], r0 + r1 + r2);
        else if (t == 6) atomicAdd(&out[16], r0 + r1 + r2);
        else {
            int base = (t < 5) ? t * 3 : 17 + (t - 7) * 3;
            atomicAdd(&out[base + 0], r0);
            atomicAdd(&out[base + 1], r1);
            atomicAdd(&out[base + 2], r2);
        }
    }
}

// ==================== launch ====================

extern "C" void kernel_launch(void* const* d_in, const int* in_sizes, int n_in,
                              void* d_out, int out_size, void* d_ws, size_t ws_size,
                              hipStream_t stream) {
    const int* eb_input = (const int*)d_in[0];
    // d_in[1] (eb_offset) irrelevant: sum over all bags == sum over all indices.
    const float* W = (const float*)d_in[2];
    float* out = (float*)d_out;
    int n_idx = in_sizes[0];

    const int nsrc = (n_idx + CHUNK - 1) / CHUNK;
    const size_t scat_bytes = (size_t)MAXSRC * CHUNK * 2;        // 8,388,608
    const size_t gs_off = scat_bytes;
    const size_t gs_bytes = (size_t)MAXSRC * GSTRIDE * 4;        // 1,048,576
    const size_t hist_off = gs_off + gs_bytes;
    const size_t hist_bytes = (size_t)VOCAB * 4;                 // 4,000,000
    const size_t part_off = (hist_off + hist_bytes + 255) & ~(size_t)255;
    const size_t need = part_off + (size_t)NSERIES * PSTRIDE * 4; // ~13.9 MB

    if (nsrc <= MAXSRC && ws_size >= need) {
        unsigned short* scat = (unsigned short*)d_ws;
        unsigned int* gs32 = (unsigned int*)((char*)d_ws + gs_off);
        unsigned int* hist = (unsigned int*)((char*)d_ws + hist_off);
        float* partials = (float*)((char*)d_ws + part_off);

        const int* idxp = eb_input;
        const float* Wp = W;
        int n = n_idx, ns = nsrc;
        unsigned short* scatp = scat;
        unsigned int* gsp = gs32;
        unsigned int* histp = hist;
        float* partp = partials;
        float* outp = out;
        void* kargs[] = { (void*)&idxp, (void*)&n, (void*)&ns, (void*)&Wp,
                          (void*)&scatp, (void*)&gsp, (void*)&histp,
                          (void*)&partp, (void*)&outp };
        hipError_t e = hipLaunchCooperativeKernel(
            reinterpret_cast<void*>(mono_kernel), dim3(GBLK), dim3(GTHR),
            kargs, 0, stream);
        if (e != hipSuccess) {
            (void)hipGetLastError();   // clear sticky error; use split path
            k_scatter<<<nsrc, GTHR, 0, stream>>>(eb_input, n_idx, nsrc, scat, gs32);
            k_hist<<<NBUCKETS, GTHR, 0, stream>>>(scat, gs32, nsrc, hist);
            k_reduce<<<GBLK, GTHR, 0, stream>>>(W, hist, partials);
            k_final<<<1, GTHR, 0, stream>>>(partials, out);
        }
    } else {
        unsigned int* hist = (unsigned int*)d_ws;
        int zblocks = (VOCAB / 4 + 255) / 256;
        zero_kernel_fb<<<zblocks, 256, 0, stream>>>(hist, out);
        int hthreads = (n_idx + 3) / 4;
        int hblocks = (hthreads + 255) / 256;
        hist_kernel_fb<<<hblocks, 256, 0, stream>>>(eb_input, hist, n_idx);
        reduce_kernel_fb<<<NUM_TABLES * 64, 256, 0, stream>>>(W, hist, out);
    }
}

// Round 7
// 466.514 us; speedup vs baseline: 2.1333x; 2.1333x over previous
//
#include <hip/hip_runtime.h>

#define VOCAB 1000000
#define NUM_TABLES 10
#define OUT_SIZE 26
#define BUCKET_BITS 12
#define BPB 4096                 // bins per bucket
#define NBUCKETS 245             // ceil(1e6/4096)
#define CHUNK 16384              // indices per scatter block (~67-elem segments)
#define MAXSRC 256               // max source chunks (n <= 4.19M)
#define GSTRIDE 256              // gs32 row stride per src (>= NBUCKETS)
#define NGROUPS (VOCAB / 4)      // 250000 4-row groups
#define RBLK ((NGROUPS + 255) / 256)   // 977 reduce blocks
#define NPW (RBLK * 4)           // per-wave partial slots per series
#define NSERIES 30               // 10 tables x 3 dims

// ---------------- fast path ----------------

// Partition 16384 indices/block by bucket (idx>>12) into the block's PRIVATE
// dense region. No global atomics; pass-2 permutation staged in LDS, dumped
// coalesced. 1024 threads, 16 elements each. (R4-proven.)
__global__ void __launch_bounds__(1024) scatter_kernel(
    const int* __restrict__ idx, int n,
    unsigned short* __restrict__ scat,   // [nsrc][CHUNK] u16 (bin within bucket)
    unsigned int* __restrict__ gs32,     // [src][GSTRIDE]: start | count<<16
    unsigned int* __restrict__ counter)  // zeroed here for reduce's last-block trick
{
    __shared__ unsigned int lcount[256];
    __shared__ unsigned int sc[256];
    __shared__ __align__(16) unsigned short stage[CHUNK];   // 32 KB
    const int tid = threadIdx.x;
    if (blockIdx.x == 0 && tid == 0) *counter = 0u;   // reduce launches after us
    if (tid < 256) lcount[tid] = 0u;
    __syncthreads();

    const int4* idx4 = (const int4*)idx;
    const int n4 = n >> 2;
    const int base4 = blockIdx.x * (CHUNK / 4);
    int4 q[4];
    bool val[4];
    unsigned rank[16];
    unsigned bkt[16];
#pragma unroll
    for (int j = 0; j < 4; ++j) {
        int i4 = base4 + j * 1024 + tid;
        val[j] = (i4 < n4);
        if (val[j]) q[j] = idx4[i4];
    }
    // pass 1: per-element rank within (block, bucket)
#pragma unroll
    for (int j = 0; j < 4; ++j) {
        if (val[j]) {
            unsigned v[4] = {(unsigned)q[j].x, (unsigned)q[j].y, (unsigned)q[j].z, (unsigned)q[j].w};
#pragma unroll
            for (int e = 0; e < 4; ++e) {
                bkt[j * 4 + e] = v[e] >> BUCKET_BITS;
                rank[j * 4 + e] = atomicAdd(&lcount[bkt[j * 4 + e]], 1u);
            }
        }
    }
    // tail (n%4): last block, thread 0 (dead code for n=4M)
    unsigned trank[3], tbkt[3];
    int tcnt = 0;
    if (blockIdx.x == gridDim.x - 1 && tid == 0) {
        for (int i = n4 * 4; i < n; ++i) {
            unsigned u = (unsigned)idx[i];
            tbkt[tcnt] = u >> BUCKET_BITS;
            trank[tcnt] = atomicAdd(&lcount[tbkt[tcnt]], 1u);
            ++tcnt;
        }
    }
    __syncthreads();
    // inclusive scan over 245 bucket counts (first 256 threads; padded to 256)
    unsigned cnt = 0;
    if (tid < 256) {
        cnt = (tid < NBUCKETS) ? lcount[tid] : 0u;
        sc[tid] = cnt;
    }
    __syncthreads();
#pragma unroll
    for (int off = 1; off < 256; off <<= 1) {
        unsigned v = 0, a = 0;
        if (tid < 256) {
            v = sc[tid];
            if (tid >= off) a = sc[tid - off];
        }
        __syncthreads();
        if (tid < 256) sc[tid] = v + a;
        __syncthreads();
    }
    if (tid < 256) {
        unsigned excl = sc[tid] - cnt;
        if (tid < NBUCKETS) gs32[(size_t)blockIdx.x * GSTRIDE + tid] = excl | (cnt << 16);
        lcount[tid] = excl;   // reuse as per-bucket base
    }
    __syncthreads();
    // pass 2: scatter into LDS stage (unique positions, no atomics)
#pragma unroll
    for (int j = 0; j < 4; ++j) {
        if (val[j]) {
            unsigned v[4] = {(unsigned)q[j].x, (unsigned)q[j].y, (unsigned)q[j].z, (unsigned)q[j].w};
#pragma unroll
            for (int e = 0; e < 4; ++e) {
                unsigned k = j * 4 + e;
                stage[lcount[bkt[k]] + rank[k]] = (unsigned short)(v[e] & (BPB - 1));
            }
        }
    }
    if (blockIdx.x == gridDim.x - 1 && tid == 0) {
        for (int i = 0; i < tcnt; ++i) {
            unsigned u = (unsigned)idx[n4 * 4 + i];
            stage[lcount[tbkt[i]] + trank[i]] = (unsigned short)(u & (BPB - 1));
        }
    }
    __syncthreads();
    // coalesced dump: 16384 u16 = 2048 uint4
    uint4* dst = (uint4*)(scat + (size_t)blockIdx.x * CHUNK);
    const uint4* src = (const uint4*)stage;
#pragma unroll
    for (int j = 0; j < 2; ++j) dst[j * 1024 + tid] = src[j * 1024 + tid];
}

// One block per bucket. The block's gs32 column is staged into LDS first
// (245 parallel loads, one latency round) so the wave segment loop has NO
// global dependency chain (R4: load gs32 -> deref p was a ~450-cycle serial
// chain per segment). Wave-cooperative segment walk stays (coalesced).
__global__ void __launch_bounds__(1024) bucket_hist_kernel(
    const unsigned short* __restrict__ scat,
    const unsigned int* __restrict__ gs32, int nsrc,
    unsigned int* __restrict__ hist)
{
    __shared__ __align__(16) unsigned int h[BPB];   // 16 KB
    __shared__ unsigned int gcol[MAXSRC];           // 1 KB staged column
    const int b = blockIdx.x;
    const int tid = threadIdx.x;
    ((uint4*)h)[tid] = make_uint4(0u, 0u, 0u, 0u);  // 1024 * uint4 = 4096
    if (tid < nsrc) gcol[tid] = gs32[(size_t)tid * GSTRIDE + b];
    __syncthreads();
    const int wave = tid >> 6, lane = tid & 63;
    for (int s = wave; s < nsrc; s += 16) {
        unsigned g32 = gcol[s];                      // LDS broadcast, no chain
        unsigned st = g32 & 0xffffu, c = g32 >> 16;
        const unsigned short* p = scat + (size_t)s * CHUNK + st;
        for (unsigned k = lane; k < c; k += 64)
            atomicAdd(&h[p[k]], 1u);
    }
    __syncthreads();
    int nb4 = min(BPB, VOCAB - b * BPB) >> 2;   // 1024 (144 for b=244)
    uint4* dst = (uint4*)(hist + (size_t)b * BPB);
    const uint4* src = (const uint4*)h;
    if (tid < nb4) dst[tid] = src[tid];
}

__device__ inline float wave_reduce(float v) {
#pragma unroll
    for (int o = 32; o > 0; o >>= 1) v += __shfl_down(v, o, 64);
    return v;
}

// Reduce: one 4-row group per thread; hist loaded ONCE into registers and
// reused across all 10 tables (kills the 10x hist re-read: 160 MB -> 124 MB).
// Per-wave partials (no barriers in the table loop). Last-arriving block does
// the final 30-series sum inline (rocPRIM pattern: release fence + atomic
// counter + acquire fence; counter pre-zeroed by scatter_kernel).
__global__ void __launch_bounds__(256) reduce_kernel(
    const float* __restrict__ W,
    const unsigned int* __restrict__ hist,
    float* __restrict__ partials,        // [NSERIES][NPW]
    unsigned int* __restrict__ counter,
    float* __restrict__ out)
{
    const int tid = threadIdx.x;
    const int g = blockIdx.x * 256 + tid;
    const int wave = tid >> 6, lane = tid & 63;
    const bool act = (g < NGROUPS);
    uint4 c4 = make_uint4(0u, 0u, 0u, 0u);
    if (act) c4 = ((const uint4*)hist)[g];
    const float c0 = (float)c4.x, c1 = (float)c4.y, c2 = (float)c4.z, c3 = (float)c4.w;
    const int pb = blockIdx.x * 4 + wave;
#pragma unroll 2
    for (int t = 0; t < NUM_TABLES; ++t) {
        float a0 = 0.f, a1 = 0.f, a2 = 0.f;
        if (act) {
            const float4* __restrict__ W4 = (const float4*)(W + (size_t)t * VOCAB * 3);
            float4 w0 = W4[3 * g + 0];
            float4 w1 = W4[3 * g + 1];
            float4 w2 = W4[3 * g + 2];
            a0 = c0 * w0.x + c1 * w0.w + c2 * w1.z + c3 * w2.y;
            a1 = c0 * w0.y + c1 * w1.x + c2 * w1.w + c3 * w2.z;
            a2 = c0 * w0.z + c1 * w1.y + c2 * w2.x + c3 * w2.w;
        }
        a0 = wave_reduce(a0);
        a1 = wave_reduce(a1);
        a2 = wave_reduce(a2);
        if (lane == 0) {
            partials[(size_t)(t * 3 + 0) * NPW + pb] = a0;
            partials[(size_t)(t * 3 + 1) * NPW + pb] = a1;
            partials[(size_t)(t * 3 + 2) * NPW + pb] = a2;
        }
    }
    // last-block-done final reduction
    __threadfence();                       // release: partials visible device-wide
    __shared__ unsigned int done;
    if (tid == 0) done = atomicAdd(counter, 1u);
    __syncthreads();
    if (done != (unsigned)gridDim.x - 1u) return;
    __threadfence();                       // acquire: see all blocks' partials

    __shared__ float smf[32];
    const int srs = tid >> 3, j = tid & 7;  // 8 threads per series
    float v = 0.f;
    if (srs < NSERIES) {
        const float* p = partials + (size_t)srs * NPW;
        for (int i = j; i < NPW; i += 8) v += p[i];
    }
#pragma unroll
    for (int off = 4; off > 0; off >>= 1) v += __shfl_down(v, off, 8);
    if (srs < NSERIES && j == 0) smf[srs] = v;
    __syncthreads();
    if (tid < OUT_SIZE) {
        float r;
        if (tid < 15) r = smf[tid];
        else if (tid == 15) r = smf[15] + smf[16] + smf[17];
        else if (tid == 16) r = smf[18] + smf[19] + smf[20];
        else r = smf[tid + 4];
        out[tid] = r;
    }
}

// ---------------- fallback path (proven) ----------------

__global__ void zero_kernel_fb(unsigned int* __restrict__ hist, float* __restrict__ out) {
    int i = blockIdx.x * blockDim.x + threadIdx.x;
    int n4 = VOCAB / 4;
    if (i < n4) ((uint4*)hist)[i] = make_uint4(0u, 0u, 0u, 0u);
    if (i < OUT_SIZE) out[i] = 0.0f;
}

__global__ void hist_kernel_fb(const int* __restrict__ idx, unsigned int* __restrict__ hist, int n) {
    int i = blockIdx.x * blockDim.x + threadIdx.x;
    int i4 = i * 4;
    if (i4 + 3 < n) {
        int4 v = ((const int4*)idx)[i];
        atomicAdd(&hist[v.x], 1u);
        atomicAdd(&hist[v.y], 1u);
        atomicAdd(&hist[v.z], 1u);
        atomicAdd(&hist[v.w], 1u);
    } else {
        for (int j = i4; j < n; ++j) atomicAdd(&hist[idx[j]], 1u);
    }
}

__global__ void __launch_bounds__(256) reduce_kernel_fb(const float* __restrict__ W,
                                                        const unsigned int* __restrict__ hist,
                                                        float* __restrict__ out) {
    const int t = blockIdx.x / 64;
    const int b = blockIdx.x % 64;
    const float4* __restrict__ W4 = (const float4*)(W + (size_t)t * VOCAB * 3);
    const uint4* __restrict__ h4 = (const uint4*)hist;
    const int ngroups = VOCAB / 4;
    float a0 = 0.f, a1 = 0.f, a2 = 0.f;
    const int stride = 64 * 256;
    for (int g = b * 256 + (int)threadIdx.x; g < ngroups; g += stride) {
        uint4 c4 = h4[g];
        float4 w0 = W4[3 * g + 0];
        float4 w1 = W4[3 * g + 1];
        float4 w2 = W4[3 * g + 2];
        float c0 = (float)c4.x, c1 = (float)c4.y, c2 = (float)c4.z, c3 = (float)c4.w;
        a0 += c0 * w0.x + c1 * w0.w + c2 * w1.z + c3 * w2.y;
        a1 += c0 * w0.y + c1 * w1.x + c2 * w1.w + c3 * w2.z;
        a2 += c0 * w0.z + c1 * w1.y + c2 * w2.x + c3 * w2.w;
    }
    a0 = wave_reduce(a0);
    a1 = wave_reduce(a1);
    a2 = wave_reduce(a2);
    __shared__ float s[3][4];
    int wave = threadIdx.x >> 6;
    int lane = threadIdx.x & 63;
    if (lane == 0) { s[0][wave] = a0; s[1][wave] = a1; s[2][wave] = a2; }
    __syncthreads();
    if (threadIdx.x == 0) {
        float r0 = s[0][0] + s[0][1] + s[0][2] + s[0][3];
        float r1 = s[1][0] + s[1][1] + s[1][2] + s[1][3];
        float r2 = s[2][0] + s[2][1] + s[2][2] + s[2][3];
        if (t == 5) atomicAdd(&out[15], r0 + r1 + r2);
        else if (t == 6) atomicAdd(&out[16], r0 + r1 + r2);
        else {
            int base = (t < 5) ? t * 3 : 17 + (t - 7) * 3;
            atomicAdd(&out[base + 0], r0);
            atomicAdd(&out[base + 1], r1);
            atomicAdd(&out[base + 2], r2);
        }
    }
}

// ---------------- launch ----------------

extern "C" void kernel_launch(void* const* d_in, const int* in_sizes, int n_in,
                              void* d_out, int out_size, void* d_ws, size_t ws_size,
                              hipStream_t stream) {
    const int* eb_input = (const int*)d_in[0];
    // d_in[1] (eb_offset) irrelevant: sum over all bags == sum over all indices.
    const float* W = (const float*)d_in[2];
    float* out = (float*)d_out;
    int n_idx = in_sizes[0];

    const int nsrc = (n_idx + CHUNK - 1) / CHUNK;
    const size_t scat_bytes = (size_t)MAXSRC * CHUNK * 2;        // 8,388,608
    const size_t gs_off = scat_bytes;
    const size_t gs_bytes = (size_t)MAXSRC * GSTRIDE * 4;        // 262,144
    const size_t hist_off = gs_off + gs_bytes;
    const size_t hist_bytes = (size_t)VOCAB * 4;                 // 4,000,000
    const size_t part_off = (hist_off + hist_bytes + 255) & ~(size_t)255;
    const size_t part_bytes = (size_t)NSERIES * NPW * 4;         // 468,960
    const size_t cnt_off = (part_off + part_bytes + 255) & ~(size_t)255;
    const size_t need = cnt_off + 256;                           // ~13.1 MB

    if (nsrc <= MAXSRC && ws_size >= need) {
        unsigned short* scat = (unsigned short*)d_ws;
        unsigned int* gs32 = (unsigned int*)((char*)d_ws + gs_off);
        unsigned int* hist = (unsigned int*)((char*)d_ws + hist_off);
        float* partials = (float*)((char*)d_ws + part_off);
        unsigned int* counter = (unsigned int*)((char*)d_ws + cnt_off);

        scatter_kernel<<<nsrc, 1024, 0, stream>>>(eb_input, n_idx, scat, gs32, counter);
        bucket_hist_kernel<<<NBUCKETS, 1024, 0, stream>>>(scat, gs32, nsrc, hist);
        reduce_kernel<<<RBLK, 256, 0, stream>>>(W, hist, partials, counter, out);
    } else {
        unsigned int* hist = (unsigned int*)d_ws;
        int zblocks = (VOCAB / 4 + 255) / 256;
        zero_kernel_fb<<<zblocks, 256, 0, stream>>>(hist, out);
        int hthreads = (n_idx + 3) / 4;
        int hblocks = (hthreads + 255) / 256;
        hist_kernel_fb<<<hblocks, 256, 0, stream>>>(eb_input, hist, n_idx);
        reduce_kernel_fb<<<NUM_TABLES * 64, 256, 0, stream>>>(W, hist, out);
    }
}

// Round 8
// 205.978 us; speedup vs baseline: 4.8316x; 2.2649x over previous
//
#include <hip/hip_runtime.h>

#define VOCAB 1000000
#define NUM_TABLES 10
#define OUT_SIZE 26
#define BUCKET_BITS 12
#define BPB 4096                 // bins per bucket
#define NBUCKETS 245             // ceil(1e6/4096)
#define CHUNK 16384              // indices per scatter block (~67-elem segments)
#define MAXSRC 256               // max source chunks (n <= 4.19M)
#define GSTRIDE 256              // gs32 row stride per src (>= NBUCKETS)
#define NGROUPS (VOCAB / 4)      // 250000 4-row groups
#define RBLK ((NGROUPS + 255) / 256)   // 977 reduce blocks
#define NSERIES 30               // 10 tables x 3 dims

// ---------------- fast path ----------------

// Partition 16384 indices/block by bucket (idx>>12) into the block's PRIVATE
// dense region. No global atomics; pass-2 permutation staged in LDS, dumped
// coalesced. 1024 threads, 16 elements each. (R4-proven.)
__global__ void __launch_bounds__(1024) scatter_kernel(
    const int* __restrict__ idx, int n,
    unsigned short* __restrict__ scat,   // [nsrc][CHUNK] u16 (bin within bucket)
    unsigned int* __restrict__ gs32)     // [src][GSTRIDE]: start | count<<16
{
    __shared__ unsigned int lcount[256];
    __shared__ unsigned int sc[256];
    __shared__ __align__(16) unsigned short stage[CHUNK];   // 32 KB
    const int tid = threadIdx.x;
    if (tid < 256) lcount[tid] = 0u;
    __syncthreads();

    const int4* idx4 = (const int4*)idx;
    const int n4 = n >> 2;
    const int base4 = blockIdx.x * (CHUNK / 4);
    int4 q[4];
    bool val[4];
    unsigned rank[16];
    unsigned bkt[16];
#pragma unroll
    for (int j = 0; j < 4; ++j) {
        int i4 = base4 + j * 1024 + tid;
        val[j] = (i4 < n4);
        if (val[j]) q[j] = idx4[i4];
    }
    // pass 1: per-element rank within (block, bucket)
#pragma unroll
    for (int j = 0; j < 4; ++j) {
        if (val[j]) {
            unsigned v[4] = {(unsigned)q[j].x, (unsigned)q[j].y, (unsigned)q[j].z, (unsigned)q[j].w};
#pragma unroll
            for (int e = 0; e < 4; ++e) {
                bkt[j * 4 + e] = v[e] >> BUCKET_BITS;
                rank[j * 4 + e] = atomicAdd(&lcount[bkt[j * 4 + e]], 1u);
            }
        }
    }
    // tail (n%4): last block, thread 0 (dead code for n=4M)
    unsigned trank[3], tbkt[3];
    int tcnt = 0;
    if (blockIdx.x == gridDim.x - 1 && tid == 0) {
        for (int i = n4 * 4; i < n; ++i) {
            unsigned u = (unsigned)idx[i];
            tbkt[tcnt] = u >> BUCKET_BITS;
            trank[tcnt] = atomicAdd(&lcount[tbkt[tcnt]], 1u);
            ++tcnt;
        }
    }
    __syncthreads();
    // inclusive scan over 245 bucket counts (first 256 threads; padded to 256)
    unsigned cnt = 0;
    if (tid < 256) {
        cnt = (tid < NBUCKETS) ? lcount[tid] : 0u;
        sc[tid] = cnt;
    }
    __syncthreads();
#pragma unroll
    for (int off = 1; off < 256; off <<= 1) {
        unsigned v = 0, a = 0;
        if (tid < 256) {
            v = sc[tid];
            if (tid >= off) a = sc[tid - off];
        }
        __syncthreads();
        if (tid < 256) sc[tid] = v + a;
        __syncthreads();
    }
    if (tid < 256) {
        unsigned excl = sc[tid] - cnt;
        if (tid < NBUCKETS) gs32[(size_t)blockIdx.x * GSTRIDE + tid] = excl | (cnt << 16);
        lcount[tid] = excl;   // reuse as per-bucket base
    }
    __syncthreads();
    // pass 2: scatter into LDS stage (unique positions, no atomics)
#pragma unroll
    for (int j = 0; j < 4; ++j) {
        if (val[j]) {
            unsigned v[4] = {(unsigned)q[j].x, (unsigned)q[j].y, (unsigned)q[j].z, (unsigned)q[j].w};
#pragma unroll
            for (int e = 0; e < 4; ++e) {
                unsigned k = j * 4 + e;
                stage[lcount[bkt[k]] + rank[k]] = (unsigned short)(v[e] & (BPB - 1));
            }
        }
    }
    if (blockIdx.x == gridDim.x - 1 && tid == 0) {
        for (int i = 0; i < tcnt; ++i) {
            unsigned u = (unsigned)idx[n4 * 4 + i];
            stage[lcount[tbkt[i]] + trank[i]] = (unsigned short)(u & (BPB - 1));
        }
    }
    __syncthreads();
    // coalesced dump: 16384 u16 = 2048 uint4
    uint4* dst = (uint4*)(scat + (size_t)blockIdx.x * CHUNK);
    const uint4* src = (const uint4*)stage;
#pragma unroll
    for (int j = 0; j < 2; ++j) dst[j * 1024 + tid] = src[j * 1024 + tid];
}

// One block per bucket. The block's gs32 column is staged into LDS first
// (<=256 parallel loads, one latency round) so the wave segment loop has NO
// global dependency chain. Wave-cooperative segment walk (coalesced).
__global__ void __launch_bounds__(1024) bucket_hist_kernel(
    const unsigned short* __restrict__ scat,
    const unsigned int* __restrict__ gs32, int nsrc,
    unsigned int* __restrict__ hist)
{
    __shared__ __align__(16) unsigned int h[BPB];   // 16 KB
    __shared__ unsigned int gcol[MAXSRC];           // 1 KB staged column
    const int b = blockIdx.x;
    const int tid = threadIdx.x;
    ((uint4*)h)[tid] = make_uint4(0u, 0u, 0u, 0u);  // 1024 * uint4 = 4096
    if (tid < nsrc) gcol[tid] = gs32[(size_t)tid * GSTRIDE + b];
    __syncthreads();
    const int wave = tid >> 6, lane = tid & 63;
    for (int s = wave; s < nsrc; s += 16) {
        unsigned g32 = gcol[s];                      // LDS broadcast, no chain
        unsigned st = g32 & 0xffffu, c = g32 >> 16;
        const unsigned short* p = scat + (size_t)s * CHUNK + st;
        for (unsigned k = lane; k < c; k += 64)
            atomicAdd(&h[p[k]], 1u);
    }
    __syncthreads();
    int nb4 = min(BPB, VOCAB - b * BPB) >> 2;   // 1024 (144 for b=244)
    uint4* dst = (uint4*)(hist + (size_t)b * BPB);
    const uint4* src = (const uint4*)h;
    if (tid < nb4) dst[tid] = src[tid];
}

__device__ inline float wave_reduce(float v) {
#pragma unroll
    for (int o = 32; o > 0; o >>= 1) v += __shfl_down(v, o, 64);
    return v;
}

// Reduce: one 4-row group per thread; hist loaded ONCE into registers and
// reused across all 10 tables (kills the 10x hist re-read: 160 MB -> 124 MB).
// LDS wave-combine -> one partial per (series, block). NO device-scope
// atomics/fences (R7's last-block-done pattern cost ~250us: 977 same-address
// cross-XCD atomics serialize at ~600-800 cycles each).
__global__ void __launch_bounds__(256) reduce_kernel(
    const float* __restrict__ W,
    const unsigned int* __restrict__ hist,
    float* __restrict__ partials)        // [NSERIES][RBLK]
{
    const int tid = threadIdx.x;
    const int g = blockIdx.x * 256 + tid;
    const int wave = tid >> 6, lane = tid & 63;
    const bool act = (g < NGROUPS);
    uint4 c4 = make_uint4(0u, 0u, 0u, 0u);
    if (act) c4 = ((const uint4*)hist)[g];
    const float c0 = (float)c4.x, c1 = (float)c4.y, c2 = (float)c4.z, c3 = (float)c4.w;
    __shared__ float sm[4][32];
#pragma unroll 2
    for (int t = 0; t < NUM_TABLES; ++t) {
        float a0 = 0.f, a1 = 0.f, a2 = 0.f;
        if (act) {
            const float4* __restrict__ W4 = (const float4*)(W + (size_t)t * VOCAB * 3);
            float4 w0 = W4[3 * g + 0];
            float4 w1 = W4[3 * g + 1];
            float4 w2 = W4[3 * g + 2];
            a0 = c0 * w0.x + c1 * w0.w + c2 * w1.z + c3 * w2.y;
            a1 = c0 * w0.y + c1 * w1.x + c2 * w1.w + c3 * w2.z;
            a2 = c0 * w0.z + c1 * w1.y + c2 * w2.x + c3 * w2.w;
        }
        a0 = wave_reduce(a0);
        a1 = wave_reduce(a1);
        a2 = wave_reduce(a2);
        if (lane == 0) {
            sm[wave][t * 3 + 0] = a0;
            sm[wave][t * 3 + 1] = a1;
            sm[wave][t * 3 + 2] = a2;
        }
    }
    __syncthreads();
    if (tid < NSERIES) {
        float v = sm[0][tid] + sm[1][tid] + sm[2][tid] + sm[3][tid];
        partials[(size_t)tid * RBLK + blockIdx.x] = v;
    }
}

// Final: 32 threads per series over 977 per-block partials (R4-proven shape).
__global__ void __launch_bounds__(1024) final_kernel(const float* __restrict__ partials,
                                                     float* __restrict__ out) {
    __shared__ float ts[32];
    const int tid = threadIdx.x;
    const int srs = tid >> 5;      // series 0..31 (use <30)
    const int j = tid & 31;
    float v = 0.f;
    if (srs < NSERIES) {
        const float* p = partials + (size_t)srs * RBLK;
#pragma unroll
        for (int k = 0; k < (RBLK + 31) / 32; ++k) {
            int i = k * 32 + j;
            if (i < RBLK) v += p[i];
        }
    }
#pragma unroll
    for (int off = 16; off > 0; off >>= 1) v += __shfl_down(v, off);
    if (j == 0 && srs < NSERIES) ts[srs] = v;
    __syncthreads();
    if (tid < OUT_SIZE) {
        float r;
        if (tid < 15) r = ts[tid];
        else if (tid == 15) r = ts[15] + ts[16] + ts[17];
        else if (tid == 16) r = ts[18] + ts[19] + ts[20];
        else r = ts[tid + 4];
        out[tid] = r;
    }
}

// ---------------- fallback path (proven) ----------------

__global__ void zero_kernel_fb(unsigned int* __restrict__ hist, float* __restrict__ out) {
    int i = blockIdx.x * blockDim.x + threadIdx.x;
    int n4 = VOCAB / 4;
    if (i < n4) ((uint4*)hist)[i] = make_uint4(0u, 0u, 0u, 0u);
    if (i < OUT_SIZE) out[i] = 0.0f;
}

__global__ void hist_kernel_fb(const int* __restrict__ idx, unsigned int* __restrict__ hist, int n) {
    int i = blockIdx.x * blockDim.x + threadIdx.x;
    int i4 = i * 4;
    if (i4 + 3 < n) {
        int4 v = ((const int4*)idx)[i];
        atomicAdd(&hist[v.x], 1u);
        atomicAdd(&hist[v.y], 1u);
        atomicAdd(&hist[v.z], 1u);
        atomicAdd(&hist[v.w], 1u);
    } else {
        for (int j = i4; j < n; ++j) atomicAdd(&hist[idx[j]], 1u);
    }
}

__global__ void __launch_bounds__(256) reduce_kernel_fb(const float* __restrict__ W,
                                                        const unsigned int* __restrict__ hist,
                                                        float* __restrict__ out) {
    const int t = blockIdx.x / 64;
    const int b = blockIdx.x % 64;
    const float4* __restrict__ W4 = (const float4*)(W + (size_t)t * VOCAB * 3);
    const uint4* __restrict__ h4 = (const uint4*)hist;
    const int ngroups = VOCAB / 4;
    float a0 = 0.f, a1 = 0.f, a2 = 0.f;
    const int stride = 64 * 256;
    for (int g = b * 256 + (int)threadIdx.x; g < ngroups; g += stride) {
        uint4 c4 = h4[g];
        float4 w0 = W4[3 * g + 0];
        float4 w1 = W4[3 * g + 1];
        float4 w2 = W4[3 * g + 2];
        float c0 = (float)c4.x, c1 = (float)c4.y, c2 = (float)c4.z, c3 = (float)c4.w;
        a0 += c0 * w0.x + c1 * w0.w + c2 * w1.z + c3 * w2.y;
        a1 += c0 * w0.y + c1 * w1.x + c2 * w1.w + c3 * w2.z;
        a2 += c0 * w0.z + c1 * w1.y + c2 * w2.x + c3 * w2.w;
    }
    a0 = wave_reduce(a0);
    a1 = wave_reduce(a1);
    a2 = wave_reduce(a2);
    __shared__ float s[3][4];
    int wave = threadIdx.x >> 6;
    int lane = threadIdx.x & 63;
    if (lane == 0) { s[0][wave] = a0; s[1][wave] = a1; s[2][wave] = a2; }
    __syncthreads();
    if (threadIdx.x == 0) {
        float r0 = s[0][0] + s[0][1] + s[0][2] + s[0][3];
        float r1 = s[1][0] + s[1][1] + s[1][2] + s[1][3];
        float r2 = s[2][0] + s[2][1] + s[2][2] + s[2][3];
        if (t == 5) atomicAdd(&out[15], r0 + r1 + r2);
        else if (t == 6) atomicAdd(&out[16], r0 + r1 + r2);
        else {
            int base = (t < 5) ? t * 3 : 17 + (t - 7) * 3;
            atomicAdd(&out[base + 0], r0);
            atomicAdd(&out[base + 1], r1);
            atomicAdd(&out[base + 2], r2);
        }
    }
}

// ---------------- launch ----------------

extern "C" void kernel_launch(void* const* d_in, const int* in_sizes, int n_in,
                              void* d_out, int out_size, void* d_ws, size_t ws_size,
                              hipStream_t stream) {
    const int* eb_input = (const int*)d_in[0];
    // d_in[1] (eb_offset) irrelevant: sum over all bags == sum over all indices.
    const float* W = (const float*)d_in[2];
    float* out = (float*)d_out;
    int n_idx = in_sizes[0];

    const int nsrc = (n_idx + CHUNK - 1) / CHUNK;
    const size_t scat_bytes = (size_t)MAXSRC * CHUNK * 2;        // 8,388,608
    const size_t gs_off = scat_bytes;
    const size_t gs_bytes = (size_t)MAXSRC * GSTRIDE * 4;        // 262,144
    const size_t hist_off = gs_off + gs_bytes;
    const size_t hist_bytes = (size_t)VOCAB * 4;                 // 4,000,000
    const size_t part_off = (hist_off + hist_bytes + 255) & ~(size_t)255;
    const size_t part_bytes = (size_t)NSERIES * RBLK * 4;        // 117,240
    const size_t need = part_off + part_bytes;                   // ~12.8 MB

    if (nsrc <= MAXSRC && ws_size >= need) {
        unsigned short* scat = (unsigned short*)d_ws;
        unsigned int* gs32 = (unsigned int*)((char*)d_ws + gs_off);
        unsigned int* hist = (unsigned int*)((char*)d_ws + hist_off);
        float* partials = (float*)((char*)d_ws + part_off);

        scatter_kernel<<<nsrc, 1024, 0, stream>>>(eb_input, n_idx, scat, gs32);
        bucket_hist_kernel<<<NBUCKETS, 1024, 0, stream>>>(scat, gs32, nsrc, hist);
        reduce_kernel<<<RBLK, 256, 0, stream>>>(W, hist, partials);
        final_kernel<<<1, 1024, 0, stream>>>(partials, out);
    } else {
        unsigned int* hist = (unsigned int*)d_ws;
        int zblocks = (VOCAB / 4 + 255) / 256;
        zero_kernel_fb<<<zblocks, 256, 0, stream>>>(hist, out);
        int hthreads = (n_idx + 3) / 4;
        int hblocks = (hthreads + 255) / 256;
        hist_kernel_fb<<<hblocks, 256, 0, stream>>>(eb_input, hist, n_idx);
        reduce_kernel_fb<<<NUM_TABLES * 64, 256, 0, stream>>>(W, hist, out);
    }
}

// Round 9
// 205.359 us; speedup vs baseline: 4.8462x; 1.0030x over previous
//
#include <hip/hip_runtime.h>

#define VOCAB 1000000
#define NUM_TABLES 10
#define OUT_SIZE 26
#define BUCKET_BITS 12
#define BPB 4096                 // bins per bucket
#define NBUCKETS 245             // ceil(1e6/4096)
#define CHUNK 16384              // indices per scatter block (~67-elem segments)
#define MAXSRC 256               // max source chunks (n <= 4.19M)
#define GSTRIDE 256              // gs32 row stride per src (>= NBUCKETS)
#define NGROUPS (VOCAB / 4)      // 250000 4-row groups
#define NSERIES 30               // 10 tables x 3 dims

// ---------------- fast path ----------------

// Partition 16384 indices/block by bucket (idx>>12) into the block's PRIVATE
// dense region. No global atomics; pass-2 permutation staged in LDS, dumped
// coalesced. 1024 threads, 16 elements each. (R4/R8-proven.)
__global__ void __launch_bounds__(1024) scatter_kernel(
    const int* __restrict__ idx, int n,
    unsigned short* __restrict__ scat,   // [nsrc][CHUNK] u16 (bin within bucket)
    unsigned int* __restrict__ gs32)     // [src][GSTRIDE]: start | count<<16
{
    __shared__ unsigned int lcount[256];
    __shared__ unsigned int sc[256];
    __shared__ __align__(16) unsigned short stage[CHUNK];   // 32 KB
    const int tid = threadIdx.x;
    if (tid < 256) lcount[tid] = 0u;
    __syncthreads();

    const int4* idx4 = (const int4*)idx;
    const int n4 = n >> 2;
    const int base4 = blockIdx.x * (CHUNK / 4);
    int4 q[4];
    bool val[4];
    unsigned rank[16];
    unsigned bkt[16];
#pragma unroll
    for (int j = 0; j < 4; ++j) {
        int i4 = base4 + j * 1024 + tid;
        val[j] = (i4 < n4);
        if (val[j]) q[j] = idx4[i4];
    }
    // pass 1: per-element rank within (block, bucket)
#pragma unroll
    for (int j = 0; j < 4; ++j) {
        if (val[j]) {
            unsigned v[4] = {(unsigned)q[j].x, (unsigned)q[j].y, (unsigned)q[j].z, (unsigned)q[j].w};
#pragma unroll
            for (int e = 0; e < 4; ++e) {
                bkt[j * 4 + e] = v[e] >> BUCKET_BITS;
                rank[j * 4 + e] = atomicAdd(&lcount[bkt[j * 4 + e]], 1u);
            }
        }
    }
    // tail (n%4): last block, thread 0 (dead code for n=4M)
    unsigned trank[3], tbkt[3];
    int tcnt = 0;
    if (blockIdx.x == gridDim.x - 1 && tid == 0) {
        for (int i = n4 * 4; i < n; ++i) {
            unsigned u = (unsigned)idx[i];
            tbkt[tcnt] = u >> BUCKET_BITS;
            trank[tcnt] = atomicAdd(&lcount[tbkt[tcnt]], 1u);
            ++tcnt;
        }
    }
    __syncthreads();
    // inclusive scan over 245 bucket counts (first 256 threads; padded to 256)
    unsigned cnt = 0;
    if (tid < 256) {
        cnt = (tid < NBUCKETS) ? lcount[tid] : 0u;
        sc[tid] = cnt;
    }
    __syncthreads();
#pragma unroll
    for (int off = 1; off < 256; off <<= 1) {
        unsigned v = 0, a = 0;
        if (tid < 256) {
            v = sc[tid];
            if (tid >= off) a = sc[tid - off];
        }
        __syncthreads();
        if (tid < 256) sc[tid] = v + a;
        __syncthreads();
    }
    if (tid < 256) {
        unsigned excl = sc[tid] - cnt;
        if (tid < NBUCKETS) gs32[(size_t)blockIdx.x * GSTRIDE + tid] = excl | (cnt << 16);
        lcount[tid] = excl;   // reuse as per-bucket base
    }
    __syncthreads();
    // pass 2: scatter into LDS stage (unique positions, no atomics)
#pragma unroll
    for (int j = 0; j < 4; ++j) {
        if (val[j]) {
            unsigned v[4] = {(unsigned)q[j].x, (unsigned)q[j].y, (unsigned)q[j].z, (unsigned)q[j].w};
#pragma unroll
            for (int e = 0; e < 4; ++e) {
                unsigned k = j * 4 + e;
                stage[lcount[bkt[k]] + rank[k]] = (unsigned short)(v[e] & (BPB - 1));
            }
        }
    }
    if (blockIdx.x == gridDim.x - 1 && tid == 0) {
        for (int i = 0; i < tcnt; ++i) {
            unsigned u = (unsigned)idx[n4 * 4 + i];
            stage[lcount[tbkt[i]] + trank[i]] = (unsigned short)(u & (BPB - 1));
        }
    }
    __syncthreads();
    // coalesced dump: 16384 u16 = 2048 uint4
    uint4* dst = (uint4*)(scat + (size_t)blockIdx.x * CHUNK);
    const uint4* src = (const uint4*)stage;
#pragma unroll
    for (int j = 0; j < 2; ++j) dst[j * 1024 + tid] = src[j * 1024 + tid];
}

__device__ inline float wave_reduce(float v) {
#pragma unroll
    for (int o = 32; o > 0; o >>= 1) v += __shfl_down(v, o, 64);
    return v;
}

// FUSED hist+reduce: one block per bucket, 1024 threads.
// Phase A: wave-cooperative gather of bucket b's bins into LDS hist
//   (gcol staged first -> no global dep chain; lanes stride each contiguous
//   ~67-elem segment -> coalesced). Hist NEVER touches global memory.
// Phase B: thread tid owns 4-row group (b*1024+tid); counts read from LDS,
//   reused across all 10 tables via a LOOP with 3 live accumulators +
//   per-table wave_reduce (R1's fused attempt died on 30-accumulator spill
//   + per-thread gather; both causes fixed here).
// Saves vs split: 4 MB hist write + 4 MB hist read + one launch boundary.
__global__ void __launch_bounds__(1024) bucket_reduce_kernel(
    const unsigned short* __restrict__ scat,
    const unsigned int* __restrict__ gs32, int nsrc,
    const float* __restrict__ W,
    float* __restrict__ partials)        // [NSERIES][NBUCKETS]
{
    __shared__ __align__(16) unsigned int h[BPB];   // 16 KB
    __shared__ unsigned int gcol[MAXSRC];           // 1 KB staged column
    __shared__ float sm[16][32];                    // 2 KB wave partials
    const int b = blockIdx.x;
    const int tid = threadIdx.x;
    const int wave = tid >> 6, lane = tid & 63;

    ((uint4*)h)[tid] = make_uint4(0u, 0u, 0u, 0u);  // 1024 * uint4 = 4096 bins
    if (tid < nsrc) gcol[tid] = gs32[(size_t)tid * GSTRIDE + b];
    __syncthreads();
    for (int s = wave; s < nsrc; s += 16) {
        unsigned g32 = gcol[s];                      // LDS broadcast, no chain
        unsigned st = g32 & 0xffffu, c = g32 >> 16;
        const unsigned short* p = scat + (size_t)s * CHUNK + st;
        for (unsigned k = lane; k < c; k += 64)
            atomicAdd(&h[p[k]], 1u);
    }
    __syncthreads();

    // Phase B: counts from LDS, stream W for 10 tables
    const int g = b * 1024 + tid;                    // global 4-row group
    const bool act = (g < NGROUPS);                  // bucket 244: 144 groups
    uint4 c4 = ((const uint4*)h)[tid];               // LDS read (always safe)
    const float c0 = (float)c4.x, c1 = (float)c4.y, c2 = (float)c4.z, c3 = (float)c4.w;
#pragma unroll 2
    for (int t = 0; t < NUM_TABLES; ++t) {
        float a0 = 0.f, a1 = 0.f, a2 = 0.f;
        if (act) {
            const float4* __restrict__ W4 = (const float4*)(W + (size_t)t * VOCAB * 3);
            float4 w0 = W4[3 * g + 0];
            float4 w1 = W4[3 * g + 1];
            float4 w2 = W4[3 * g + 2];
            a0 = c0 * w0.x + c1 * w0.w + c2 * w1.z + c3 * w2.y;
            a1 = c0 * w0.y + c1 * w1.x + c2 * w1.w + c3 * w2.z;
            a2 = c0 * w0.z + c1 * w1.y + c2 * w2.x + c3 * w2.w;
        }
        a0 = wave_reduce(a0);
        a1 = wave_reduce(a1);
        a2 = wave_reduce(a2);
        if (lane == 0) {
            sm[wave][t * 3 + 0] = a0;
            sm[wave][t * 3 + 1] = a1;
            sm[wave][t * 3 + 2] = a2;
        }
    }
    __syncthreads();
    if (tid < NSERIES) {
        float v = 0.f;
#pragma unroll
        for (int w = 0; w < 16; ++w) v += sm[w][tid];
        partials[(size_t)tid * NBUCKETS + b] = v;
    }
}

// Final: 32 threads per series over 245 per-bucket partials.
__global__ void __launch_bounds__(1024) final_kernel(const float* __restrict__ partials,
                                                     float* __restrict__ out) {
    __shared__ float ts[32];
    const int tid = threadIdx.x;
    const int srs = tid >> 5;      // series 0..31 (use <30)
    const int j = tid & 31;
    float v = 0.f;
    if (srs < NSERIES) {
        const float* p = partials + (size_t)srs * NBUCKETS;
#pragma unroll
        for (int k = 0; k < (NBUCKETS + 31) / 32; ++k) {
            int i = k * 32 + j;
            if (i < NBUCKETS) v += p[i];
        }
    }
#pragma unroll
    for (int off = 16; off > 0; off >>= 1) v += __shfl_down(v, off);
    if (j == 0 && srs < NSERIES) ts[srs] = v;
    __syncthreads();
    if (tid < OUT_SIZE) {
        float r;
        if (tid < 15) r = ts[tid];
        else if (tid == 15) r = ts[15] + ts[16] + ts[17];
        else if (tid == 16) r = ts[18] + ts[19] + ts[20];
        else r = ts[tid + 4];
        out[tid] = r;
    }
}

// ---------------- fallback path (proven) ----------------

__global__ void zero_kernel_fb(unsigned int* __restrict__ hist, float* __restrict__ out) {
    int i = blockIdx.x * blockDim.x + threadIdx.x;
    int n4 = VOCAB / 4;
    if (i < n4) ((uint4*)hist)[i] = make_uint4(0u, 0u, 0u, 0u);
    if (i < OUT_SIZE) out[i] = 0.0f;
}

__global__ void hist_kernel_fb(const int* __restrict__ idx, unsigned int* __restrict__ hist, int n) {
    int i = blockIdx.x * blockDim.x + threadIdx.x;
    int i4 = i * 4;
    if (i4 + 3 < n) {
        int4 v = ((const int4*)idx)[i];
        atomicAdd(&hist[v.x], 1u);
        atomicAdd(&hist[v.y], 1u);
        atomicAdd(&hist[v.z], 1u);
        atomicAdd(&hist[v.w], 1u);
    } else {
        for (int j = i4; j < n; ++j) atomicAdd(&hist[idx[j]], 1u);
    }
}

__global__ void __launch_bounds__(256) reduce_kernel_fb(const float* __restrict__ W,
                                                        const unsigned int* __restrict__ hist,
                                                        float* __restrict__ out) {
    const int t = blockIdx.x / 64;
    const int b = blockIdx.x % 64;
    const float4* __restrict__ W4 = (const float4*)(W + (size_t)t * VOCAB * 3);
    const uint4* __restrict__ h4 = (const uint4*)hist;
    const int ngroups = VOCAB / 4;
    float a0 = 0.f, a1 = 0.f, a2 = 0.f;
    const int stride = 64 * 256;
    for (int g = b * 256 + (int)threadIdx.x; g < ngroups; g += stride) {
        uint4 c4 = h4[g];
        float4 w0 = W4[3 * g + 0];
        float4 w1 = W4[3 * g + 1];
        float4 w2 = W4[3 * g + 2];
        float c0 = (float)c4.x, c1 = (float)c4.y, c2 = (float)c4.z, c3 = (float)c4.w;
        a0 += c0 * w0.x + c1 * w0.w + c2 * w1.z + c3 * w2.y;
        a1 += c0 * w0.y + c1 * w1.x + c2 * w1.w + c3 * w2.z;
        a2 += c0 * w0.z + c1 * w1.y + c2 * w2.x + c3 * w2.w;
    }
    a0 = wave_reduce(a0);
    a1 = wave_reduce(a1);
    a2 = wave_reduce(a2);
    __shared__ float s[3][4];
    int wave = threadIdx.x >> 6;
    int lane = threadIdx.x & 63;
    if (lane == 0) { s[0][wave] = a0; s[1][wave] = a1; s[2][wave] = a2; }
    __syncthreads();
    if (threadIdx.x == 0) {
        float r0 = s[0][0] + s[0][1] + s[0][2] + s[0][3];
        float r1 = s[1][0] + s[1][1] + s[1][2] + s[1][3];
        float r2 = s[2][0] + s[2][1] + s[2][2] + s[2][3];
        if (t == 5) atomicAdd(&out[15], r0 + r1 + r2);
        else if (t == 6) atomicAdd(&out[16], r0 + r1 + r2);
        else {
            int base = (t < 5) ? t * 3 : 17 + (t - 7) * 3;
            atomicAdd(&out[base + 0], r0);
            atomicAdd(&out[base + 1], r1);
            atomicAdd(&out[base + 2], r2);
        }
    }
}

// ---------------- launch ----------------

extern "C" void kernel_launch(void* const* d_in, const int* in_sizes, int n_in,
                              void* d_out, int out_size, void* d_ws, size_t ws_size,
                              hipStream_t stream) {
    const int* eb_input = (const int*)d_in[0];
    // d_in[1] (eb_offset) irrelevant: sum over all bags == sum over all indices.
    const float* W = (const float*)d_in[2];
    float* out = (float*)d_out;
    int n_idx = in_sizes[0];

    const int nsrc = (n_idx + CHUNK - 1) / CHUNK;
    const size_t scat_bytes = (size_t)MAXSRC * CHUNK * 2;        // 8,388,608
    const size_t gs_off = scat_bytes;
    const size_t gs_bytes = (size_t)MAXSRC * GSTRIDE * 4;        // 262,144
    const size_t part_off = (gs_off + gs_bytes + 255) & ~(size_t)255;
    const size_t part_bytes = (size_t)NSERIES * NBUCKETS * 4;    // 29,400
    const size_t need = part_off + part_bytes;                   // ~8.7 MB

    if (nsrc <= MAXSRC && ws_size >= need) {
        unsigned short* scat = (unsigned short*)d_ws;
        unsigned int* gs32 = (unsigned int*)((char*)d_ws + gs_off);
        float* partials = (float*)((char*)d_ws + part_off);

        scatter_kernel<<<nsrc, 1024, 0, stream>>>(eb_input, n_idx, scat, gs32);
        bucket_reduce_kernel<<<NBUCKETS, 1024, 0, stream>>>(scat, gs32, nsrc, W, partials);
        final_kernel<<<1, 1024, 0, stream>>>(partials, out);
    } else {
        unsigned int* hist = (unsigned int*)d_ws;
        int zblocks = (VOCAB / 4 + 255) / 256;
        zero_kernel_fb<<<zblocks, 256, 0, stream>>>(hist, out);
        int hthreads = (n_idx + 3) / 4;
        int hblocks = (hthreads + 255) / 256;
        hist_kernel_fb<<<hblocks, 256, 0, stream>>>(eb_input, hist, n_idx);
        reduce_kernel_fb<<<NUM_TABLES * 64, 256, 0, stream>>>(W, hist, out);
    }
}